// Round 5
// baseline (494.256 us; speedup 1.0000x reference)
//
#include <hip/hip_runtime.h>
#include <hip/hip_bf16.h>

using bf16 = __hip_bfloat16;

constexpr int B  = 8;
constexpr int N0 = 8192;
constexpr int NS = 2048;
constexpr int CP = 512;
constexpr int CS = 256;
constexpr int C1 = 256;
constexpr int C2 = 256;
constexpr int K1 = CP + CS;          // 768
constexpr int COLS = B * N0;         // 65536
constexpr float BN_EPS = 1e-3f;
constexpr float SLOPE  = 0.01f;

typedef short  short8 __attribute__((ext_vector_type(8)));
typedef float  f32x4  __attribute__((ext_vector_type(4)));

typedef __attribute__((address_space(1))) unsigned int gas_uint;
typedef __attribute__((address_space(3))) unsigned int las_uint;

// raw barrier + compiler memory fences (keeps C++ LDS ops from crossing)
#define BARX() do { asm volatile("" ::: "memory"); __builtin_amdgcn_s_barrier(); asm volatile("" ::: "memory"); } while (0)
#define VM12()  asm volatile("s_waitcnt vmcnt(12)" ::: "memory")
#define VM0()   asm volatile("s_waitcnt vmcnt(0)"  ::: "memory")
#define LGKM0() asm volatile("s_waitcnt lgkmcnt(0)" ::: "memory")

// manual RNE fp32->bf16 (no NaNs in this workload) and back
__device__ __forceinline__ unsigned short f2bu(float f) {
  unsigned int u = __float_as_uint(f);
  return (unsigned short)((u + 0x7fffu + ((u >> 16) & 1u)) >> 16);
}
__device__ __forceinline__ float bu2f(unsigned short v) {
  return __uint_as_float((unsigned int)v << 16);
}

// ---------------- prep: fp32 weights -> bf16 (row-major [M][K]), zero stats ----------------
__global__ __launch_bounds__(256) void prep_kernel(
    const float* __restrict__ W1, const float* __restrict__ W2,
    unsigned short* __restrict__ W1b, unsigned short* __restrict__ W2b,
    float* __restrict__ stats)
{
  int id = blockIdx.x * 256 + threadIdx.x;
  if (id < 1024) stats[id] = 0.0f;
  if (id < C1 * K1) W1b[id] = f2bu(W1[id]);
  if (id < C2 * C1) W2b[id] = f2bu(W2[id]);
}

// =======================================================================
// 3-NN, slice-split: block = 64 queries x 4 slices (256 thr).
// v5: each thread runs TWO independent top-3 chains (low/high half of its
// 512-point range) for ILP, pre-merges them (stable: low-j chain first,
// strict <), then the 4-slice LDS merge as before. Bit-exact selection.
// =======================================================================
__global__ __launch_bounds__(256) void knn_kernel(
    const float* __restrict__ xyz, const float* __restrict__ xyz_prev,
    float* __restrict__ wq, int* __restrict__ iq)
{
#pragma clang fp contract(off)
  __shared__ float4 sp[NS];                 // x,y,z,|p|^2  (32 KB)
  __shared__ float  md[4][64][3];
  __shared__ int    mi[4][64][3];
  const int b = blockIdx.y;
  const float* xp = xyz_prev + (size_t)b * 3 * NS;
  for (int j = threadIdx.x; j < NS; j += 256) {
    float x = xp[j], y = xp[NS + j], z = xp[2 * NS + j];
    sp[j] = make_float4(x, y, z, (x * x + y * y) + z * z);   // numpy association
  }
  __syncthreads();

  const int q  = threadIdx.x & 63;
  const int sl = threadIdx.x >> 6;
  const int n  = blockIdx.x * 64 + q;
  const float* xq = xyz + (size_t)b * 3 * N0;
  float qx = xq[n], qy = xq[N0 + n], qz = xq[2 * N0 + n];
  float qq = (qx * qx + qy * qy) + qz * qz;

  const int j0 = sl * (NS / 4);             // 512-point range
  float a0 = 1e30f, a1 = 1e30f, a2 = 1e30f;
  int   ai0 = 0, ai1 = 0, ai2 = 0;
  float c0 = 1e30f, c1 = 1e30f, c2 = 1e30f;
  int   ci0 = 0, ci1 = 0, ci2 = 0;
#pragma unroll 2
  for (int jj = 0; jj < NS / 8; ++jj) {     // 256 iters, 2 points each
    const int ja = j0 + jj, jc = j0 + NS / 8 + jj;
    float4 pa = sp[ja];
    float4 pc = sp[jc];
    float dota = (qx * pa.x + qy * pa.y) + qz * pa.z;
    float da = (qq + pa.w) - 2.0f * dota;   // numpy association
    float dotc = (qx * pc.x + qy * pc.y) + qz * pc.z;
    float dc = (qq + pc.w) - 2.0f * dotc;
    if (da < a0)      { a2 = a1; ai2 = ai1; a1 = a0; ai1 = ai0; a0 = da; ai0 = ja; }
    else if (da < a1) { a2 = a1; ai2 = ai1; a1 = da; ai1 = ja; }
    else if (da < a2) { a2 = da; ai2 = ja; }
    if (dc < c0)      { c2 = c1; ci2 = ci1; c1 = c0; ci1 = ci0; c0 = dc; ci0 = jc; }
    else if (dc < c1) { c2 = c1; ci2 = ci1; c1 = dc; ci1 = jc; }
    else if (dc < c2) { c2 = dc; ci2 = jc; }
  }
  // pre-merge chain C into chain A (all C indices > all A indices; strict <
  // + insertion order == single ascending scan -> stable like top_k)
  {
    float dv[3] = {c0, c1, c2}; int iv[3] = {ci0, ci1, ci2};
#pragma unroll
    for (int t = 0; t < 3; ++t) {
      float d = dv[t]; int ii = iv[t];
      if (d < a0)      { a2 = a1; ai2 = ai1; a1 = a0; ai1 = ai0; a0 = d; ai0 = ii; }
      else if (d < a1) { a2 = a1; ai2 = ai1; a1 = d;  ai1 = ii; }
      else if (d < a2) { a2 = d;  ai2 = ii; }
    }
  }
  md[sl][q][0] = a0; md[sl][q][1] = a1; md[sl][q][2] = a2;
  mi[sl][q][0] = ai0; mi[sl][q][1] = ai1; mi[sl][q][2] = ai2;
  __syncthreads();

  if (threadIdx.x < 64) {
    float e0 = 1e30f, e1 = 1e30f, e2 = 1e30f;
    int   k0 = 0, k1 = 0, k2 = 0;
#pragma unroll
    for (int s = 0; s < 4; ++s) {
#pragma unroll
      for (int t = 0; t < 3; ++t) {
        float d = md[s][q][t]; int ii = mi[s][q][t];
        if (d < e0)      { e2 = e1; k2 = k1; e1 = e0; k1 = k0; e0 = d; k0 = ii; }
        else if (d < e1) { e2 = e1; k2 = k1; e1 = d;  k1 = ii; }
        else if (d < e2) { e2 = d;  k2 = ii; }
      }
    }
    e0 = fmaxf(e0, 1e-10f); e1 = fmaxf(e1, 1e-10f); e2 = fmaxf(e2, 1e-10f);
    float v0 = 1.0f / (e0 + 1e-8f), v1 = 1.0f / (e1 + 1e-8f), v2 = 1.0f / (e2 + 1e-8f);
    float s = (v0 + v1) + v2;
    const int gi = (b * N0 + n) * 3;
    wq[gi + 0] = v0 / s; wq[gi + 1] = v1 / s; wq[gi + 2] = v2 / s;
    iq[gi + 0] = k0;     iq[gi + 1] = k1;     iq[gi + 2] = k2;
  }
}

// =======================================================================
// interp: LDS-gather. Block = (b, 16-channel group, n-half).
// =======================================================================
__global__ __launch_bounds__(256) void interp_kernel(
    const float* __restrict__ feat_prev, const int* __restrict__ iq,
    const float* __restrict__ wq, unsigned short* __restrict__ Xt)
{
  __shared__ unsigned short sf[16 * 2048];        // 64 KB
  const int bx = blockIdx.x;                      // 512 blocks
  const int b  = bx >> 6;
  const int cg = (bx >> 1) & 31;
  const int nh = bx & 1;
  const int c0 = cg * 16;
  const float* fp = feat_prev + ((size_t)b * CP + c0) * NS;

  for (int id = threadIdx.x; id < 8192; id += 256) {
    float4 v = reinterpret_cast<const float4*>(fp)[id];
    ushort4 o;
    o.x = f2bu(v.x); o.y = f2bu(v.y); o.z = f2bu(v.z); o.w = f2bu(v.w);
    *reinterpret_cast<ushort4*>(&sf[id * 4]) = o;
  }
  __syncthreads();

  const int nbase = nh * 4096;
  for (int it = 0; it < 16; ++it) {
    const int n    = nbase + it * 256 + threadIdx.x;
    const int gcol = b * N0 + n;
    const int gq   = gcol * 3;
    const int i0 = iq[gq], i1 = iq[gq + 1], i2 = iq[gq + 2];
    const float w0 = wq[gq], w1 = wq[gq + 1], w2 = wq[gq + 2];
    unsigned short outv[16];
#pragma unroll
    for (int c = 0; c < 16; ++c) {
      const unsigned short* row = &sf[c * 2048];
      float v = w0 * bu2f(row[i0]) + w1 * bu2f(row[i1]) + w2 * bu2f(row[i2]);
      outv[c] = f2bu(v);
    }
    unsigned short* dst = Xt + (size_t)gcol * K1 + c0;
    *reinterpret_cast<short8*>(dst)     = *reinterpret_cast<short8*>(&outv[0]);
    *reinterpret_cast<short8*>(dst + 8) = *reinterpret_cast<short8*>(&outv[8]);
  }
}

// =======================================================================
// skipT: transpose skip fp32 [c][n] -> Xt[n][512+c] bf16. Tile 64x64.
// =======================================================================
__global__ __launch_bounds__(256) void skipt_kernel(
    const float* __restrict__ skip, unsigned short* __restrict__ Xt)
{
  __shared__ float T[64][65];
  const int kt   = blockIdx.x & 3;
  const int ct   = blockIdx.x >> 2;
  const int col0 = ct * 64;
  const int b    = col0 >> 13;
  const int n0   = col0 & 8191;
  const float* src = skip + ((size_t)b * CS + kt * 64) * N0 + n0;

  for (int id = threadIdx.x; id < 1024; id += 256) {
    int r = id >> 4, q = id & 15;
    float4 v = *reinterpret_cast<const float4*>(src + (size_t)r * N0 + q * 4);
    T[r][q * 4 + 0] = v.x; T[r][q * 4 + 1] = v.y;
    T[r][q * 4 + 2] = v.z; T[r][q * 4 + 3] = v.w;
  }
  __syncthreads();
  for (int id = threadIdx.x; id < 512; id += 256) {
    int n = id >> 3, q = id & 7;
    alignas(16) unsigned short tmp[8];
#pragma unroll
    for (int j = 0; j < 8; ++j) tmp[j] = f2bu(T[q * 8 + j][n]);
    *reinterpret_cast<short8*>(Xt + (size_t)(col0 + n) * K1 + CP + kt * 64 + q * 8) =
        *reinterpret_cast<short8*>(tmp);
  }
}

// =======================================================================
// MFMA GEMM1 v5: BM=256 x BN=128, BK=64, 4 waves. Depth-2 pipeline with
// COUNTED vmcnt + raw s_barrier (T4): stages for k and k+1 always in
// flight; s_waitcnt vmcnt(12) retires stage(k) only (12 = exact vmem ops
// per phase: 4 gload_lds + 8 A dwordx4). __syncthreads (vmcnt-0 drain)
// eliminated from the loop. Epilogue: LDS-transposed coalesced Y1t write
// (kills the 2.3x partial-line write amplification seen in R3/R4).
// =======================================================================
__global__ __launch_bounds__(256, 2) void gemm1_kernel(
    const unsigned short* __restrict__ W1b, const unsigned short* __restrict__ Xt,
    unsigned short* __restrict__ Y1t, float* __restrict__ stats)
{
  __shared__ unsigned short Bs[2][128 * 64];   // 32 KB  [buf][n][k]
  __shared__ unsigned short scr[64][264];      // 33.8 KB epilogue transpose (264 = pad)

  const int tid   = threadIdx.x;
  const int gcol0 = blockIdx.x * 128;

  const int wv = tid >> 6, lane = tid & 63;
  const int wm = wv * 64;                  // wave's 64 M-rows (BM=256)
  const int qm = lane & 15, quad = lane >> 4;
  const int lr = lane >> 3, lc = lane & 7;
  const int sw_src = (lc ^ lr) * 8;        // inverse-swizzled source k-offset
  const int sw_rd  = qm & 7;               // read-side XOR key

  f32x4 acc[4][8];
#pragma unroll
  for (int i = 0; i < 4; ++i)
#pragma unroll
    for (int j = 0; j < 8; ++j) acc[i][j] = (f32x4){0.f, 0.f, 0.f, 0.f};

  auto stageB = [&](int kt, int buf) {     // 4 vmem ops
    const int kof = kt * 64 + sw_src;
#pragma unroll
    for (int t = 0; t < 4; ++t) {
      const int ch = wv * 4 + t;           // 0..15 (1 KB chunks)
      const int r  = ch * 8 + lr;          // n-row 0..127
      __builtin_amdgcn_global_load_lds(
          (const gas_uint*)(Xt + (size_t)(gcol0 + r) * K1 + kof),
          (las_uint*)(&Bs[buf][ch * 512]), 16, 0, 0);
    }
  };
  auto loadA = [&](int kt, short8 (&af)[2][4]) {   // 8 vmem ops
#pragma unroll
    for (int h = 0; h < 2; ++h)
#pragma unroll
      for (int i = 0; i < 4; ++i)
        af[h][i] = *reinterpret_cast<const short8*>(
            W1b + (size_t)(wm + i * 16 + qm) * K1 + kt * 64 + h * 32 + quad * 8);
  };
  auto compute = [&](const short8 (&af)[2][4], int buf) {
    const unsigned short* Bb = &Bs[buf][0];
#pragma unroll
    for (int h = 0; h < 2; ++h) {
      short8 bf[8];
#pragma unroll
      for (int j = 0; j < 8; ++j)
        bf[j] = *reinterpret_cast<const short8*>(
            &Bb[(j * 16 + qm) * 64 + ((h * 4 + quad) ^ sw_rd) * 8]);
#pragma unroll
      for (int i = 0; i < 4; ++i)
#pragma unroll
        for (int j = 0; j < 8; ++j)
          acc[i][j] = __builtin_amdgcn_mfma_f32_16x16x32_bf16(af[h][i], bf[j], acc[i][j], 0, 0, 0);
    }
  };

  short8 afA[2][4], afB[2][4];
  stageB(0, 0); loadA(0, afA);             // oldest 12
  stageB(1, 1); loadA(1, afB);             // newer 12

  for (int kt = 0; kt < K1 / 64; kt += 2) {   // kt = 0,2,...,10
    VM12();                                   // retire stage(kt); stage(kt+1) stays out
    BARX();
    compute(afA, 0);
    BARX();                                   // all reads of Bs0 done
    if (kt + 2 < K1 / 64) { stageB(kt + 2, 0); loadA(kt + 2, afA); }
    if (kt < 10) { VM12(); } else { VM0(); }  // retire stage(kt+1)
    BARX();
    compute(afB, 1);
    BARX();
    if (kt + 3 < K1 / 64) { stageB(kt + 3, 1); loadA(kt + 3, afB); }
  }

  // ---- BN1 stats (from fp32 acc, unchanged math) ----
#pragma unroll
  for (int i = 0; i < 4; ++i) {
    const int mb = wm + i * 16 + quad * 4;
    float s[4] = {0.f, 0.f, 0.f, 0.f}, s2[4] = {0.f, 0.f, 0.f, 0.f};
#pragma unroll
    for (int j = 0; j < 8; ++j) {
#pragma unroll
      for (int r = 0; r < 4; ++r) {
        float v = acc[i][j][r];
        s[r] += v; s2[r] += v * v;
      }
    }
#pragma unroll
    for (int m = 1; m < 16; m <<= 1) {
#pragma unroll
      for (int r = 0; r < 4; ++r) { s[r] += __shfl_xor(s[r], m); s2[r] += __shfl_xor(s2[r], m); }
    }
    if (qm == 0) {
#pragma unroll
      for (int r = 0; r < 4; ++r) {
        atomicAdd(&stats[mb + r], s[r]);
        atomicAdd(&stats[C1 + mb + r], s2[r]);
      }
    }
  }

  // ---- coalesced Y1t write via LDS transpose (two 64-col halves) ----
#pragma unroll
  for (int half = 0; half < 2; ++half) {
#pragma unroll
    for (int i = 0; i < 4; ++i) {
      const int mb = wm + i * 16 + quad * 4;
#pragma unroll
      for (int jj = 0; jj < 4; ++jj) {
        const int j = half * 4 + jj;
        ushort4 o;
        o.x = f2bu(acc[i][j][0]); o.y = f2bu(acc[i][j][1]);
        o.z = f2bu(acc[i][j][2]); o.w = f2bu(acc[i][j][3]);
        *reinterpret_cast<ushort4*>(&scr[jj * 16 + qm][mb]) = o;
      }
    }
    LGKM0();
    BARX();
    // stream 32 KB out fully linear: 256 thr x 8 x 16 B
#pragma unroll
    for (int u = 0; u < 8; ++u) {
      const int flat = tid * 16 + u * 4096;          // byte in logical [64][512]
      const int r = flat >> 9, c = (flat & 511) >> 1; // ushort col (mult of 8)
      short8 v = *reinterpret_cast<const short8*>(&scr[r][c]);
      *reinterpret_cast<short8*>(Y1t + (((size_t)(gcol0 + half * 64 + r)) << 8) + c) = v;
    }
    if (half == 0) BARX();                 // scr reuse
  }
}

// ---------------- affine: fold BN stats + gamma/beta into scale/shift ----------------
__global__ __launch_bounds__(256) void affine_kernel(
    const float* __restrict__ s, const float* __restrict__ g,
    const float* __restrict__ bb, float* __restrict__ a)
{
  int c = threadIdx.x;
  float inv = 1.0f / (float)COLS;
  float mean = s[c] * inv;
  float var  = s[C1 + c] * inv - mean * mean;
  float sc   = g[c] / sqrtf(var + BN_EPS);
  a[c]      = sc;
  a[C1 + c] = bb[c] - mean * sc;
}

// =======================================================================
// MFMA GEMM2 v5: BM=256 x BN=128, K=256, 4 phases fully unrolled.
// ds_write-based LDS handoff -> only lgkmcnt(0) + raw barrier per phase
// (NO vmcnt drain ever). A-frags and B-regs double-buffered (static names).
// Fused bn1+LeakyReLU in the reg-staging. fp32 out + BN2 stats.
// =======================================================================
__global__ __launch_bounds__(256, 2) void gemm2_kernel(
    const unsigned short* __restrict__ W2b, const unsigned short* __restrict__ Y1t,
    const float* __restrict__ aff, float* __restrict__ out_nf,
    float* __restrict__ stats2)
{
  __shared__ unsigned short Bs[2][128][72];     // 2 x 18 KB, padded rows

  const int tid   = threadIdx.x;
  const int gcol0 = blockIdx.x * 128;
  const int b     = gcol0 >> 13;
  const int ncol0 = gcol0 & 8191;

  const int wv = tid >> 6, lane = tid & 63;
  const int wm = wv * 64;
  const int qm = lane & 15, quad = lane >> 4;
  const int sn = tid >> 1;                 // staging row 0..127
  const int sck = (tid & 1) * 4;           // staging chunk base (2 thr/row)

  f32x4 acc[4][8];
#pragma unroll
  for (int i = 0; i < 4; ++i)
#pragma unroll
    for (int j = 0; j < 8; ++j) acc[i][j] = (f32x4){0.f, 0.f, 0.f, 0.f};

  short8 afA[2][4], afB[2][4];
  short8 bregA[4], bregB[4];

  auto loadA = [&](int kt, short8 (&af)[2][4]) {
#pragma unroll
    for (int h = 0; h < 2; ++h)
#pragma unroll
      for (int i = 0; i < 4; ++i)
        af[h][i] = *reinterpret_cast<const short8*>(
            W2b + (size_t)(wm + i * 16 + qm) * C1 + kt * 64 + h * 32 + quad * 8);
  };
  auto loadB = [&](int kt, short8 (&breg)[4]) {
#pragma unroll
    for (int t = 0; t < 4; ++t)
      breg[t] = *reinterpret_cast<const short8*>(
          Y1t + (size_t)(gcol0 + sn) * C1 + kt * 64 + (sck + t) * 8);
  };
  auto xformWrite = [&](const short8 (&breg)[4], int kt, int buf) {
#pragma unroll
    for (int t = 0; t < 4; ++t) {
      const int c0 = kt * 64 + (sck + t) * 8;
      float4 sc0 = *reinterpret_cast<const float4*>(aff + c0);
      float4 sc1 = *reinterpret_cast<const float4*>(aff + c0 + 4);
      float4 sh0 = *reinterpret_cast<const float4*>(aff + C1 + c0);
      float4 sh1 = *reinterpret_cast<const float4*>(aff + C1 + c0 + 4);
      alignas(16) unsigned short tmp[8];
#pragma unroll
      for (int j = 0; j < 4; ++j) {
        float v = bu2f((unsigned short)breg[t][j]) * (&sc0.x)[j] + (&sh0.x)[j];
        v = (v >= 0.f) ? v : SLOPE * v;
        tmp[j] = f2bu(v);
      }
#pragma unroll
      for (int j = 0; j < 4; ++j) {
        float v = bu2f((unsigned short)breg[t][4 + j]) * (&sc1.x)[j] + (&sh1.x)[j];
        v = (v >= 0.f) ? v : SLOPE * v;
        tmp[4 + j] = f2bu(v);
      }
      *reinterpret_cast<short8*>(&Bs[buf][sn][(sck + t) * 8]) =
          *reinterpret_cast<short8*>(tmp);
    }
  };
  auto compute = [&](const short8 (&af)[2][4], int buf) {
#pragma unroll
    for (int h = 0; h < 2; ++h) {
      short8 bf[8];
#pragma unroll
      for (int j = 0; j < 8; ++j)
        bf[j] = *reinterpret_cast<const short8*>(
            &Bs[buf][j * 16 + qm][(h * 4 + quad) * 8]);
#pragma unroll
      for (int i = 0; i < 4; ++i)
#pragma unroll
        for (int j = 0; j < 8; ++j)
          acc[i][j] = __builtin_amdgcn_mfma_f32_16x16x32_bf16(af[h][i], bf[j], acc[i][j], 0, 0, 0);
    }
  };

  // prologue
  loadB(0, bregA); loadA(0, afA);
  loadB(1, bregB); loadA(1, afB);
  xformWrite(bregA, 0, 0);
  LGKM0(); BARX();
  // P0
  compute(afA, 0);
  xformWrite(bregB, 1, 1);
  loadB(2, bregA); loadA(2, afA);
  LGKM0(); BARX();
  // P1
  compute(afB, 1);
  xformWrite(bregA, 2, 0);
  loadB(3, bregB); loadA(3, afB);
  LGKM0(); BARX();
  // P2
  compute(afA, 0);
  xformWrite(bregB, 3, 1);
  LGKM0(); BARX();
  // P3
  compute(afB, 1);

  // epilogue: raw fp32 Y2 to out_nf [b][m][N0] + BN2 stats
#pragma unroll
  for (int i = 0; i < 4; ++i) {
    const int mb = wm + i * 16 + quad * 4;
    float s[4] = {0.f, 0.f, 0.f, 0.f}, s2[4] = {0.f, 0.f, 0.f, 0.f};
#pragma unroll
    for (int j = 0; j < 8; ++j) {
      const int col = ncol0 + j * 16 + qm;
#pragma unroll
      for (int r = 0; r < 4; ++r) {
        float v = acc[i][j][r];
        out_nf[((size_t)b * C2 + mb + r) * N0 + col] = v;
        s[r] += v; s2[r] += v * v;
      }
    }
#pragma unroll
    for (int m = 1; m < 16; m <<= 1) {
#pragma unroll
      for (int r = 0; r < 4; ++r) { s[r] += __shfl_xor(s[r], m); s2[r] += __shfl_xor(s2[r], m); }
    }
    if (qm == 0) {
#pragma unroll
      for (int r = 0; r < 4; ++r) {
        atomicAdd(&stats2[mb + r], s[r]);
        atomicAdd(&stats2[C2 + mb + r], s2[r]);
      }
    }
  }
}

// ---------------- finalize: in-place BN2 + LeakyReLU on out_nf (fp32) ----------------
__global__ __launch_bounds__(256) void finalize_kernel(float* __restrict__ nf,
                                                       const float* __restrict__ aff)
{
  int id4 = blockIdx.x * 256 + threadIdx.x;      // float4-granule index
  int e = id4 * 4;
  int c = (e % (C2 * N0)) / N0;
  float sc = aff[c], sh = aff[C1 + c];
  float4 v = reinterpret_cast<float4*>(nf)[id4];
  v.x = v.x * sc + sh; v.x = (v.x >= 0.f) ? v.x : SLOPE * v.x;
  v.y = v.y * sc + sh; v.y = (v.y >= 0.f) ? v.y : SLOPE * v.y;
  v.z = v.z * sc + sh; v.z = (v.z >= 0.f) ? v.z : SLOPE * v.z;
  v.w = v.w * sc + sh; v.w = (v.w >= 0.f) ? v.w : SLOPE * v.w;
  reinterpret_cast<float4*>(nf)[id4] = v;
}

// ---------------- copy xyz passthrough (fp32) ----------------
__global__ __launch_bounds__(256) void copy_xyz_kernel(const float* __restrict__ xyz,
                                                       float* __restrict__ out)
{
  int id = blockIdx.x * 256 + threadIdx.x;       // float4 granules, 12288 total
  reinterpret_cast<float4*>(out)[id] = reinterpret_cast<const float4*>(xyz)[id];
}

extern "C" void kernel_launch(void* const* d_in, const int* in_sizes, int n_in,
                              void* d_out, int out_size, void* d_ws, size_t ws_size,
                              hipStream_t stream)
{
  const float* xyz       = (const float*)d_in[0];
  const float* skip      = (const float*)d_in[1];
  const float* xyz_prev  = (const float*)d_in[2];
  const float* feat_prev = (const float*)d_in[3];
  const float* W1        = (const float*)d_in[4];
  const float* g1        = (const float*)d_in[5];
  const float* b1        = (const float*)d_in[6];
  const float* W2        = (const float*)d_in[7];
  const float* g2        = (const float*)d_in[8];
  const float* b2        = (const float*)d_in[9];

  float* out    = (float*)d_out;
  float* out_nf = out + (size_t)B * 3 * N0;      // [B][C2][N0] fp32

  char* ws = (char*)d_ws;
  float*          wq    = (float*)(ws + 0);                 //   786432 B
  int*            iq    = (int*)  (ws + 786432);            //   786432 B
  unsigned short* W1b   = (unsigned short*)(ws + 1572864);  //   393216 B
  unsigned short* W2b   = (unsigned short*)(ws + 1966080);  //   131072 B
  float*          stats = (float*)(ws + 2097152);           //     4096 B
  float*          aff   = (float*)(ws + 2101248);           //     4096 B
  unsigned short* Y1t   = (unsigned short*)(ws + 2105344);  // 33554432 B  [COLS][C1]
  unsigned short* Xt    = (unsigned short*)(ws + 35659776); // 100663296 B [COLS][K1]
  // total: 136,323,072 B

  prep_kernel<<<768, 256, 0, stream>>>(W1, W2, W1b, W2b, stats);
  knn_kernel<<<dim3(N0 / 64, B), 256, 0, stream>>>(xyz, xyz_prev, wq, iq);
  interp_kernel<<<512, 256, 0, stream>>>(feat_prev, iq, wq, Xt);
  skipt_kernel<<<4096, 256, 0, stream>>>(skip, Xt);
  gemm1_kernel<<<COLS / 128, 256, 0, stream>>>(W1b, Xt, Y1t, stats);
  affine_kernel<<<1, 256, 0, stream>>>(stats, g1, b1, aff);
  gemm2_kernel<<<COLS / 128, 256, 0, stream>>>(W2b, Y1t, aff, out_nf, stats + 512);
  affine_kernel<<<1, 256, 0, stream>>>(stats + 512, g2, b2, aff + 512);
  finalize_kernel<<<(C2 * N0 * B) / (4 * 256), 256, 0, stream>>>(out_nf, aff + 512);
  copy_xyz_kernel<<<(B * 3 * N0) / (4 * 256), 256, 0, stream>>>(xyz, out);
}